// Round 1
// baseline (508.868 us; speedup 1.0000x reference)
//
#include <hip/hip_runtime.h>

namespace {
constexpr int T_CTX  = 4096;
constexpr int E_DIM  = 1024;
constexpr int H_DIM  = 64;
constexpr int B_SZ   = 4;
constexpr int M_ROWS = B_SZ * T_CTX; // 16384
}

// ---------------------------------------------------------------------------
// QKV projection: out[M,64] = X[M,1024] @ W[1024,64] + bias
// BM=64, BN=64(=H), BK=64; 256 threads (16x16), 4x4 accumulator per thread.
// blockIdx.y selects q/k/v.
// ---------------------------------------------------------------------------
__global__ __launch_bounds__(256)
void qkv_proj_kernel(const float* __restrict__ x,
                     const float* __restrict__ Wq, const float* __restrict__ biasq,
                     const float* __restrict__ Wk, const float* __restrict__ biask,
                     const float* __restrict__ Wv, const float* __restrict__ biasv,
                     float* __restrict__ qo, float* __restrict__ ko, float* __restrict__ vo)
{
    const int m0    = blockIdx.x * 64;
    const int which = blockIdx.y;
    const float* W    = (which == 0) ? Wq    : (which == 1) ? Wk    : Wv;
    const float* bias = (which == 0) ? biasq : (which == 1) ? biask : biasv;
    float* out        = (which == 0) ? qo    : (which == 1) ? ko    : vo;

    __shared__ float Xs[64][64];  // [k][m]  (transposed so reads are b128 over m)
    __shared__ float Ws[64][64];  // [k][n]

    const int tid = threadIdx.x;
    const int tx  = tid & 15;   // output col group
    const int ty  = tid >> 4;   // output row group

    float acc[4][4] = {};

    for (int k0 = 0; k0 < E_DIM; k0 += 64) {
        __syncthreads();  // protect previous tile's reads
        // stage X tile (transposed) and W tile; each thread 4 float4 of each
        #pragma unroll
        for (int l = 0; l < 4; ++l) {
            const int row = ty + l * 16;            // 0..63
            const int kq  = tx * 4;
            const float4 xv = *reinterpret_cast<const float4*>(
                &x[(size_t)(m0 + row) * E_DIM + k0 + kq]);
            Xs[kq + 0][row] = xv.x;
            Xs[kq + 1][row] = xv.y;
            Xs[kq + 2][row] = xv.z;
            Xs[kq + 3][row] = xv.w;
            const int krow = ty + l * 16;
            *reinterpret_cast<float4*>(&Ws[krow][tx * 4]) =
                *reinterpret_cast<const float4*>(&W[(size_t)(k0 + krow) * H_DIM + tx * 4]);
        }
        __syncthreads();
        #pragma unroll 16
        for (int kk = 0; kk < 64; ++kk) {
            const float4 av = *reinterpret_cast<const float4*>(&Xs[kk][ty * 4]);
            const float4 bw = *reinterpret_cast<const float4*>(&Ws[kk][tx * 4]);
            const float ar[4] = {av.x, av.y, av.z, av.w};
            const float br[4] = {bw.x, bw.y, bw.z, bw.w};
            #pragma unroll
            for (int i = 0; i < 4; ++i)
                #pragma unroll
                for (int j = 0; j < 4; ++j)
                    acc[i][j] = fmaf(ar[i], br[j], acc[i][j]);
        }
    }

    const float4 bv4 = *reinterpret_cast<const float4*>(&bias[tx * 4]);
    const float badd[4] = {bv4.x, bv4.y, bv4.z, bv4.w};
    #pragma unroll
    for (int i = 0; i < 4; ++i) {
        float4 r;
        r.x = acc[i][0] + badd[0];
        r.y = acc[i][1] + badd[1];
        r.z = acc[i][2] + badd[2];
        r.w = acc[i][3] + badd[3];
        *reinterpret_cast<float4*>(&out[(size_t)(m0 + ty * 4 + i) * H_DIM + tx * 4]) = r;
    }
}

// ---------------------------------------------------------------------------
// Causal flash attention, fp32. One block per (batch, 64-row q tile).
// 256 threads (16x16), 4x4 thread tiles for S = Q K^T and O += P V.
// Online softmax (running m, l per row) via 16-lane shfl reductions.
// P reuses the Ks buffer (extra barrier between last Ks read and P write).
// ---------------------------------------------------------------------------
__global__ __launch_bounds__(256)
void attn_kernel(const float* __restrict__ q, const float* __restrict__ k,
                 const float* __restrict__ v, float* __restrict__ out)
{
    const int qt    = blockIdx.x;            // 0..63
    const int batch = blockIdx.y;            // 0..3
    const int q0    = qt * 64;
    const size_t base = (size_t)batch * T_CTX * H_DIM;

    __shared__ float Qs[64][64];  // [h][qi]  transposed
    __shared__ float Ks[64][64];  // [h][kj]  transposed; reused as P[kj][qi]
    __shared__ float Vs[64][64];  // [kj][h]

    const int tid = threadIdx.x;
    const int tx  = tid & 15;
    const int ty  = tid >> 4;

    // stage Q tile transposed (each thread 16 floats)
    {
        const int row = tid >> 3;            // 0..31
        const int h0  = (tid & 7) * 8;       // 0..56
        #pragma unroll
        for (int l = 0; l < 2; ++l) {
            const int r = row + l * 32;
            const float4 a0 = *reinterpret_cast<const float4*>(
                &q[base + (size_t)(q0 + r) * H_DIM + h0]);
            const float4 a1 = *reinterpret_cast<const float4*>(
                &q[base + (size_t)(q0 + r) * H_DIM + h0 + 4]);
            Qs[h0 + 0][r] = a0.x; Qs[h0 + 1][r] = a0.y;
            Qs[h0 + 2][r] = a0.z; Qs[h0 + 3][r] = a0.w;
            Qs[h0 + 4][r] = a1.x; Qs[h0 + 5][r] = a1.y;
            Qs[h0 + 6][r] = a1.z; Qs[h0 + 7][r] = a1.w;
        }
    }

    float o[4][4]  = {};
    float mrow[4]  = {-1e30f, -1e30f, -1e30f, -1e30f};
    float lrow[4]  = {};
    constexpr float scale = 0.125f;  // 1/sqrt(64)

    for (int kt = 0; kt <= qt; ++kt) {
        const int k0 = kt * 64;
        __syncthreads();  // prev PV reads of Ks(P)/Vs done; Q staging visible on iter 0
        // stage K (transposed) and V (row-major)
        {
            const int row = tid >> 3;
            const int h0  = (tid & 7) * 8;
            #pragma unroll
            for (int l = 0; l < 2; ++l) {
                const int r = row + l * 32;
                const float4 a0 = *reinterpret_cast<const float4*>(
                    &k[base + (size_t)(k0 + r) * H_DIM + h0]);
                const float4 a1 = *reinterpret_cast<const float4*>(
                    &k[base + (size_t)(k0 + r) * H_DIM + h0 + 4]);
                Ks[h0 + 0][r] = a0.x; Ks[h0 + 1][r] = a0.y;
                Ks[h0 + 2][r] = a0.z; Ks[h0 + 3][r] = a0.w;
                Ks[h0 + 4][r] = a1.x; Ks[h0 + 5][r] = a1.y;
                Ks[h0 + 6][r] = a1.z; Ks[h0 + 7][r] = a1.w;
                const float4 v0 = *reinterpret_cast<const float4*>(
                    &v[base + (size_t)(k0 + r) * H_DIM + h0]);
                const float4 v1 = *reinterpret_cast<const float4*>(
                    &v[base + (size_t)(k0 + r) * H_DIM + h0 + 4]);
                *reinterpret_cast<float4*>(&Vs[r][h0])     = v0;
                *reinterpret_cast<float4*>(&Vs[r][h0 + 4]) = v1;
            }
        }
        __syncthreads();

        // S = Q K^T (registers)
        float s[4][4] = {};
        #pragma unroll 8
        for (int hh = 0; hh < 64; ++hh) {
            const float4 av = *reinterpret_cast<const float4*>(&Qs[hh][ty * 4]);
            const float4 bk4 = *reinterpret_cast<const float4*>(&Ks[hh][tx * 4]);
            const float ar[4] = {av.x, av.y, av.z, av.w};
            const float br[4] = {bk4.x, bk4.y, bk4.z, bk4.w};
            #pragma unroll
            for (int i = 0; i < 4; ++i)
                #pragma unroll
                for (int j = 0; j < 4; ++j)
                    s[i][j] = fmaf(ar[i], br[j], s[i][j]);
        }

        // scale + causal mask (only the diagonal tile needs masking)
        const bool diag = (kt == qt);
        #pragma unroll
        for (int i = 0; i < 4; ++i)
            #pragma unroll
            for (int j = 0; j < 4; ++j) {
                s[i][j] *= scale;
                if (diag && (k0 + tx * 4 + j) > (q0 + ty * 4 + i)) s[i][j] = -1e30f;
            }

        __syncthreads();  // all Ks reads done before overwriting Ks with P

        // online softmax per row; write P into Ks buffer transposed [kj][qi]
        #pragma unroll
        for (int i = 0; i < 4; ++i) {
            float rm = fmaxf(fmaxf(s[i][0], s[i][1]), fmaxf(s[i][2], s[i][3]));
            rm = fmaxf(rm, __shfl_xor(rm, 1));
            rm = fmaxf(rm, __shfl_xor(rm, 2));
            rm = fmaxf(rm, __shfl_xor(rm, 4));
            rm = fmaxf(rm, __shfl_xor(rm, 8));
            const float newm = fmaxf(mrow[i], rm);
            const float cf   = __expf(mrow[i] - newm);
            float p[4];
            float rl = 0.f;
            #pragma unroll
            for (int j = 0; j < 4; ++j) { p[j] = __expf(s[i][j] - newm); rl += p[j]; }
            rl += __shfl_xor(rl, 1);
            rl += __shfl_xor(rl, 2);
            rl += __shfl_xor(rl, 4);
            rl += __shfl_xor(rl, 8);
            lrow[i] = lrow[i] * cf + rl;
            #pragma unroll
            for (int j = 0; j < 4; ++j) o[i][j] *= cf;
            mrow[i] = newm;
            #pragma unroll
            for (int j = 0; j < 4; ++j) Ks[tx * 4 + j][ty * 4 + i] = p[j];
        }
        __syncthreads();

        // O += P V
        #pragma unroll 8
        for (int kj = 0; kj < 64; ++kj) {
            const float4 av  = *reinterpret_cast<const float4*>(&Ks[kj][ty * 4]); // P
            const float4 bv4 = *reinterpret_cast<const float4*>(&Vs[kj][tx * 4]);
            const float ar[4] = {av.x, av.y, av.z, av.w};
            const float br[4] = {bv4.x, bv4.y, bv4.z, bv4.w};
            #pragma unroll
            for (int i = 0; i < 4; ++i)
                #pragma unroll
                for (int j = 0; j < 4; ++j)
                    o[i][j] = fmaf(ar[i], br[j], o[i][j]);
        }
    }

    #pragma unroll
    for (int i = 0; i < 4; ++i) {
        const float inv = 1.0f / lrow[i];
        float4 r;
        r.x = o[i][0] * inv; r.y = o[i][1] * inv;
        r.z = o[i][2] * inv; r.w = o[i][3] * inv;
        *reinterpret_cast<float4*>(
            &out[base + (size_t)(q0 + ty * 4 + i) * H_DIM + tx * 4]) = r;
    }
}

extern "C" void kernel_launch(void* const* d_in, const int* in_sizes, int n_in,
                              void* d_out, int out_size, void* d_ws, size_t ws_size,
                              hipStream_t stream) {
    const float* x  = (const float*)d_in[0];
    const float* Wq = (const float*)d_in[1];
    const float* bq = (const float*)d_in[2];
    const float* Wk = (const float*)d_in[3];
    const float* bk = (const float*)d_in[4];
    const float* Wv = (const float*)d_in[5];
    const float* bv = (const float*)d_in[6];
    float* out = (float*)d_out;

    // workspace: q, k, v each (B*T, H) fp32 = 4 MiB -> 12 MiB total
    float* qw = (float*)d_ws;
    float* kw = qw + (size_t)M_ROWS * H_DIM;
    float* vw = kw + (size_t)M_ROWS * H_DIM;

    qkv_proj_kernel<<<dim3(M_ROWS / 64, 3), 256, 0, stream>>>(
        x, Wq, bq, Wk, bk, Wv, bv, qw, kw, vw);
    attn_kernel<<<dim3(T_CTX / 64, B_SZ), 256, 0, stream>>>(qw, kw, vw, out);
}

// Round 2
// 282.793 us; speedup vs baseline: 1.7994x; 1.7994x over previous
//
#include <hip/hip_runtime.h>

typedef __attribute__((ext_vector_type(8))) short short8_t;
typedef __attribute__((ext_vector_type(4))) float f32x4;

namespace {
constexpr int T_CTX  = 4096;
constexpr int E_DIM  = 1024;
constexpr int H_DIM  = 64;
constexpr int B_SZ   = 4;
constexpr int M_ROWS = B_SZ * T_CTX; // 16384
}

__device__ __forceinline__ unsigned short f2bf(float f) {
    unsigned u = __builtin_bit_cast(unsigned, f);
    u += 0x7fffu + ((u >> 16) & 1u);          // RNE
    return (unsigned short)(u >> 16);
}
__device__ __forceinline__ float bf2f(unsigned short h) {
    unsigned u = ((unsigned)h) << 16;
    return __builtin_bit_cast(float, u);
}
__device__ __forceinline__ unsigned pack2(unsigned short lo, unsigned short hi) {
    return (unsigned)lo | ((unsigned)hi << 16);
}
// swizzled ushort index into a row-major [rows][64] bf16 LDS tile:
// byte ^= (row&7)<<4  -> ushort idx col ^= (row&7)<<3. Keeps 16B reads conflict-free.
__device__ __forceinline__ int swz(int row, int col) {
    return row * 64 + (col ^ ((row & 7) << 3));
}

// ---------------------------------------------------------------------------
// Weight prep: W[1024][64] fp32 -> Wt[64][1024] bf16 (per matrix), via LDS.
// ---------------------------------------------------------------------------
__global__ __launch_bounds__(256)
void prep_weights(const float* __restrict__ Wq, const float* __restrict__ Wk,
                  const float* __restrict__ Wv, unsigned short* __restrict__ wt)
{
    const int mat = blockIdx.y;
    const float* W = (mat == 0) ? Wq : (mat == 1) ? Wk : Wv;
    unsigned short* out = wt + (size_t)mat * H_DIM * E_DIM;
    __shared__ float Ls[64][65];
    const int tid = threadIdx.x;
    const int kb = blockIdx.x * 64;
    #pragma unroll
    for (int j = 0; j < 4; ++j) {
        int p = j * 256 + tid;
        int kr = p >> 4, c4 = (p & 15) * 4;
        float4 w4 = *reinterpret_cast<const float4*>(&W[(size_t)(kb + kr) * H_DIM + c4]);
        Ls[c4 + 0][kr] = w4.x; Ls[c4 + 1][kr] = w4.y;
        Ls[c4 + 2][kr] = w4.z; Ls[c4 + 3][kr] = w4.w;
    }
    __syncthreads();
    #pragma unroll
    for (int j = 0; j < 2; ++j) {
        int p = j * 256 + tid;
        int n = p >> 3, c8 = (p & 7) * 8;
        uint4 w;
        w.x = pack2(f2bf(Ls[n][c8 + 0]), f2bf(Ls[n][c8 + 1]));
        w.y = pack2(f2bf(Ls[n][c8 + 2]), f2bf(Ls[n][c8 + 3]));
        w.z = pack2(f2bf(Ls[n][c8 + 4]), f2bf(Ls[n][c8 + 5]));
        w.w = pack2(f2bf(Ls[n][c8 + 6]), f2bf(Ls[n][c8 + 7]));
        *reinterpret_cast<uint4*>(&out[(size_t)n * E_DIM + kb + c8]) = w;
    }
}

// ---------------------------------------------------------------------------
// QKV projection, bf16 MFMA. BM=64 (4 waves x 16 rows), N=64, BK=64.
// Emits bf16; q is pre-scaled by 1/sqrt(H)=0.125 (exact).
// ---------------------------------------------------------------------------
__global__ __launch_bounds__(256)
void proj_kernel(const float* __restrict__ x, const unsigned short* __restrict__ wt,
                 const float* __restrict__ bq, const float* __restrict__ bk,
                 const float* __restrict__ bv,
                 unsigned short* __restrict__ qb, unsigned short* __restrict__ kb,
                 unsigned short* __restrict__ vb)
{
    const int mat = blockIdx.y;
    const unsigned short* Wt = wt + (size_t)mat * H_DIM * E_DIM;
    const float* bias = (mat == 0) ? bq : (mat == 1) ? bk : bv;
    unsigned short* out = (mat == 0) ? qb : (mat == 1) ? kb : vb;
    const float osc = (mat == 0) ? 0.125f : 1.0f;

    const int m0  = blockIdx.x * 64;
    const int tid = threadIdx.x;
    const int lane = tid & 63, wv = tid >> 6;
    const int l15 = lane & 15, lg = lane >> 4;
    const int kof = lg * 8;

    __shared__ unsigned short Xs[64 * 64];
    __shared__ unsigned short Ws[64 * 64];

    f32x4 acc[4] = {};

    for (int k0 = 0; k0 < E_DIM; k0 += 64) {
        __syncthreads();
        // stage X (fp32 -> bf16), transposed-free row-major [m][k]
        #pragma unroll
        for (int j = 0; j < 4; ++j) {
            int p = j * 256 + tid;
            int row = p >> 4, c4 = (p & 15) * 4;
            float4 xv = *reinterpret_cast<const float4*>(
                &x[(size_t)(m0 + row) * E_DIM + k0 + c4]);
            uint2 wr;
            wr.x = pack2(f2bf(xv.x), f2bf(xv.y));
            wr.y = pack2(f2bf(xv.z), f2bf(xv.w));
            *reinterpret_cast<uint2*>(&Xs[swz(row, c4)]) = wr;
        }
        // stage Wt tile [n][k] (already bf16 + transposed)
        #pragma unroll
        for (int j = 0; j < 2; ++j) {
            int p = j * 256 + tid;
            int n = p >> 3, c8 = (p & 7) * 8;
            uint4 w = *reinterpret_cast<const uint4*>(&Wt[(size_t)n * E_DIM + k0 + c8]);
            *reinterpret_cast<uint4*>(&Ws[swz(n, c8)]) = w;
        }
        __syncthreads();
        #pragma unroll
        for (int hs = 0; hs < 2; ++hs) {
            short8_t a = *reinterpret_cast<const short8_t*>(&Xs[swz(wv * 16 + l15, hs * 32 + kof)]);
            #pragma unroll
            for (int oc = 0; oc < 4; ++oc) {
                short8_t b = *reinterpret_cast<const short8_t*>(&Ws[swz(oc * 16 + l15, hs * 32 + kof)]);
                acc[oc] = __builtin_amdgcn_mfma_f32_16x16x32_bf16(a, b, acc[oc], 0, 0, 0);
            }
        }
    }

    #pragma unroll
    for (int oc = 0; oc < 4; ++oc) {
        float badd = bias[oc * 16 + l15];
        #pragma unroll
        for (int r = 0; r < 4; ++r) {
            int row = m0 + wv * 16 + lg * 4 + r;
            out[(size_t)row * H_DIM + oc * 16 + l15] = f2bf((acc[oc][r] + badd) * osc);
        }
    }
}

// ---------------------------------------------------------------------------
// Causal flash attention, bf16 MFMA. 32-row q tile, 2 waves (16-row strip
// each, full kv width -> softmax stays wave-local). Descending-qt dispatch.
// ---------------------------------------------------------------------------
__global__ __launch_bounds__(128)
void attn_kernel(const unsigned short* __restrict__ qg, const unsigned short* __restrict__ kg,
                 const unsigned short* __restrict__ vg, float* __restrict__ outp)
{
    const int bx    = blockIdx.x;
    const int qt    = 127 - (bx >> 2);   // big tiles first
    const int batch = bx & 3;
    const int q0    = qt * 32;
    const size_t rbase = (size_t)batch * T_CTX;
    const int nkv  = qt / 2 + 1;         // 64-wide kv tiles

    const int tid = threadIdx.x;
    const int lane = tid & 63, wv = tid >> 6;  // wv in {0,1}
    const int l15 = lane & 15, lg = lane >> 4;
    const int kof = lg * 8;

    __shared__ unsigned short Qs[32 * 64];
    __shared__ unsigned short Ks[64 * 64];
    __shared__ unsigned short Vt[64 * 64];   // [h][kv]
    __shared__ unsigned short Pt[32 * 64];   // [q][kv]

    // stage Q (already scaled by 0.125 in proj)
    #pragma unroll
    for (int j = 0; j < 2; ++j) {
        int p = j * 128 + tid;
        int row = p >> 3, c8 = (p & 7) * 8;
        uint4 qv = *reinterpret_cast<const uint4*>(&qg[(rbase + q0 + row) * H_DIM + c8]);
        *reinterpret_cast<uint4*>(&Qs[swz(row, c8)]) = qv;
    }

    f32x4 o[4] = {};
    float mrow[4] = {-1e30f, -1e30f, -1e30f, -1e30f};
    float lrow[4] = {};

    for (int kt = 0; kt < nkv; ++kt) {
        const int k0 = kt * 64;
        __syncthreads();   // prior-iter reads done; Q visible on iter 0
        // stage K rows [kv][h]
        #pragma unroll
        for (int j = 0; j < 4; ++j) {
            int p = j * 128 + tid;
            int row = p >> 3, c8 = (p & 7) * 8;
            uint4 kv4 = *reinterpret_cast<const uint4*>(&kg[(rbase + k0 + row) * H_DIM + c8]);
            *reinterpret_cast<uint4*>(&Ks[swz(row, c8)]) = kv4;
        }
        // stage V transposed -> Vt[h][kv] (column reads: 2x64B sectors/instr)
        {
            int h = tid >> 1, half = tid & 1;
            unsigned short tmp[32];
            #pragma unroll
            for (int i = 0; i < 32; ++i)
                tmp[i] = vg[(rbase + k0 + half * 32 + i) * H_DIM + h];
            #pragma unroll
            for (int c = 0; c < 4; ++c) {
                uint4 w;
                w.x = pack2(tmp[c * 8 + 0], tmp[c * 8 + 1]);
                w.y = pack2(tmp[c * 8 + 2], tmp[c * 8 + 3]);
                w.z = pack2(tmp[c * 8 + 4], tmp[c * 8 + 5]);
                w.w = pack2(tmp[c * 8 + 6], tmp[c * 8 + 7]);
                *reinterpret_cast<uint4*>(&Vt[swz(h, half * 32 + c * 8)]) = w;
            }
        }
        __syncthreads();

        // S = Q K^T  (q pre-scaled)
        f32x4 s[4] = {};
        #pragma unroll
        for (int hs = 0; hs < 2; ++hs) {
            short8_t a = *reinterpret_cast<const short8_t*>(&Qs[swz(wv * 16 + l15, hs * 32 + kof)]);
            #pragma unroll
            for (int ct = 0; ct < 4; ++ct) {
                short8_t b = *reinterpret_cast<const short8_t*>(&Ks[swz(ct * 16 + l15, hs * 32 + kof)]);
                s[ct] = __builtin_amdgcn_mfma_f32_16x16x32_bf16(a, b, s[ct], 0, 0, 0);
            }
        }

        if (kt == nkv - 1) {   // only the last tile can cross the diagonal
            #pragma unroll
            for (int ct = 0; ct < 4; ++ct)
                #pragma unroll
                for (int r = 0; r < 4; ++r) {
                    int col = k0 + ct * 16 + l15;
                    int row = q0 + wv * 16 + lg * 4 + r;
                    if (col > row) s[ct][r] = -1e30f;
                }
        }

        // online softmax (wave-local; rows live in 16-lane groups)
        #pragma unroll
        for (int r = 0; r < 4; ++r) {
            float mx = fmaxf(fmaxf(s[0][r], s[1][r]), fmaxf(s[2][r], s[3][r]));
            mx = fmaxf(mx, __shfl_xor(mx, 1));
            mx = fmaxf(mx, __shfl_xor(mx, 2));
            mx = fmaxf(mx, __shfl_xor(mx, 4));
            mx = fmaxf(mx, __shfl_xor(mx, 8));
            float newm = fmaxf(mrow[r], mx);
            float cf = __expf(mrow[r] - newm);
            float rl = 0.f;
            int qrl = wv * 16 + lg * 4 + r;
            #pragma unroll
            for (int ct = 0; ct < 4; ++ct) {
                float p = __expf(s[ct][r] - newm);
                rl += p;
                Pt[swz(qrl, ct * 16 + l15)] = f2bf(p);
            }
            rl += __shfl_xor(rl, 1);
            rl += __shfl_xor(rl, 2);
            rl += __shfl_xor(rl, 4);
            rl += __shfl_xor(rl, 8);
            lrow[r] = lrow[r] * cf + rl;
            mrow[r] = newm;
            #pragma unroll
            for (int oc = 0; oc < 4; ++oc) o[oc][r] *= cf;
        }
        // NOTE: no barrier needed — each wave reads back only its own Pt rows,
        // and Vt was fenced by the barrier above.

        // O += P V
        #pragma unroll
        for (int ks = 0; ks < 2; ++ks) {
            short8_t a = *reinterpret_cast<const short8_t*>(&Pt[swz(wv * 16 + l15, ks * 32 + kof)]);
            #pragma unroll
            for (int oc = 0; oc < 4; ++oc) {
                short8_t b = *reinterpret_cast<const short8_t*>(&Vt[swz(oc * 16 + l15, ks * 32 + kof)]);
                o[oc] = __builtin_amdgcn_mfma_f32_16x16x32_bf16(a, b, o[oc], 0, 0, 0);
            }
        }
    }

    float inv[4];
    #pragma unroll
    for (int r = 0; r < 4; ++r) inv[r] = 1.0f / lrow[r];
    #pragma unroll
    for (int oc = 0; oc < 4; ++oc)
        #pragma unroll
        for (int r = 0; r < 4; ++r)
            outp[(rbase + q0 + wv * 16 + lg * 4 + r) * H_DIM + oc * 16 + l15] = o[oc][r] * inv[r];
}

extern "C" void kernel_launch(void* const* d_in, const int* in_sizes, int n_in,
                              void* d_out, int out_size, void* d_ws, size_t ws_size,
                              hipStream_t stream) {
    const float* x  = (const float*)d_in[0];
    const float* Wq = (const float*)d_in[1];
    const float* bq = (const float*)d_in[2];
    const float* Wk = (const float*)d_in[3];
    const float* bk = (const float*)d_in[4];
    const float* Wv = (const float*)d_in[5];
    const float* bv = (const float*)d_in[6];
    float* out = (float*)d_out;

    // ws layout (ushort): Wt[3*64*1024] | q[16384*64] | k[...] | v[...]  ~6.4 MiB
    unsigned short* wt = (unsigned short*)d_ws;
    unsigned short* qb = wt + 3 * H_DIM * E_DIM;
    unsigned short* kb = qb + (size_t)M_ROWS * H_DIM;
    unsigned short* vb = kb + (size_t)M_ROWS * H_DIM;

    prep_weights<<<dim3(E_DIM / 64, 3), 256, 0, stream>>>(Wq, Wk, Wv, wt);
    proj_kernel<<<dim3(M_ROWS / 64, 3), 256, 0, stream>>>(x, wt, bq, bk, bv, qb, kb, vb);
    attn_kernel<<<dim3((T_CTX / 32) * B_SZ), 128, 0, stream>>>(qb, kb, vb, out);
}

// Round 3
// 187.270 us; speedup vs baseline: 2.7173x; 1.5101x over previous
//
#include <hip/hip_runtime.h>

typedef __attribute__((ext_vector_type(8))) short short8_t;
typedef __attribute__((ext_vector_type(4))) float f32x4;

namespace {
constexpr int T_CTX  = 4096;
constexpr int E_DIM  = 1024;
constexpr int H_DIM  = 64;
constexpr int B_SZ   = 4;
constexpr int M_ROWS = B_SZ * T_CTX; // 16384
}

__device__ __forceinline__ unsigned short f2bf(float f) {
    unsigned u = __builtin_bit_cast(unsigned, f);
    u += 0x7fffu + ((u >> 16) & 1u);          // RNE
    return (unsigned short)(u >> 16);
}
__device__ __forceinline__ unsigned pack2(unsigned short lo, unsigned short hi) {
    return (unsigned)lo | ((unsigned)hi << 16);
}
// swizzled ushort index into a row-major [rows][64] bf16 LDS tile
__device__ __forceinline__ int swz(int row, int col) {
    return row * 64 + (col ^ ((row & 7) << 3));
}

// ---------------------------------------------------------------------------
// Weight prep: W[1024][64] fp32 -> Wt[64][1024] bf16 (per matrix), via LDS.
// ---------------------------------------------------------------------------
__global__ __launch_bounds__(256)
void prep_weights(const float* __restrict__ Wq, const float* __restrict__ Wk,
                  const float* __restrict__ Wv, unsigned short* __restrict__ wt)
{
    const int mat = blockIdx.y;
    const float* W = (mat == 0) ? Wq : (mat == 1) ? Wk : Wv;
    unsigned short* out = wt + (size_t)mat * H_DIM * E_DIM;
    __shared__ float Ls[64][65];
    const int tid = threadIdx.x;
    const int kb = blockIdx.x * 64;
    #pragma unroll
    for (int j = 0; j < 4; ++j) {
        int p = j * 256 + tid;
        int kr = p >> 4, c4 = (p & 15) * 4;
        float4 w4 = *reinterpret_cast<const float4*>(&W[(size_t)(kb + kr) * H_DIM + c4]);
        Ls[c4 + 0][kr] = w4.x; Ls[c4 + 1][kr] = w4.y;
        Ls[c4 + 2][kr] = w4.z; Ls[c4 + 3][kr] = w4.w;
    }
    __syncthreads();
    #pragma unroll
    for (int j = 0; j < 2; ++j) {
        int p = j * 256 + tid;
        int n = p >> 3, c8 = (p & 7) * 8;
        uint4 w;
        w.x = pack2(f2bf(Ls[n][c8 + 0]), f2bf(Ls[n][c8 + 1]));
        w.y = pack2(f2bf(Ls[n][c8 + 2]), f2bf(Ls[n][c8 + 3]));
        w.z = pack2(f2bf(Ls[n][c8 + 4]), f2bf(Ls[n][c8 + 5]));
        w.w = pack2(f2bf(Ls[n][c8 + 6]), f2bf(Ls[n][c8 + 7]));
        *reinterpret_cast<uint4*>(&out[(size_t)n * E_DIM + kb + c8]) = w;
    }
}

// ---------------------------------------------------------------------------
// Fused QKV projection: reads x ONCE, computes q,k,v. BM=64 (4 waves x 16
// rows), BK=64. q pre-scaled by 0.125. v written TRANSPOSED: vt[b][h][t].
// ---------------------------------------------------------------------------
__global__ __launch_bounds__(256)
void proj_kernel(const float* __restrict__ x, const unsigned short* __restrict__ wt,
                 const float* __restrict__ bq, const float* __restrict__ bk,
                 const float* __restrict__ bv,
                 unsigned short* __restrict__ qb, unsigned short* __restrict__ kb,
                 unsigned short* __restrict__ vtb)
{
    const int m0    = blockIdx.x * 64;
    const int batch = m0 >> 12;         // /4096
    const int t0    = m0 & (T_CTX - 1);
    const int tid = threadIdx.x;
    const int lane = tid & 63, wv = tid >> 6;
    const int l15 = lane & 15, lg = lane >> 4;
    const int kof = lg * 8;

    __shared__ unsigned short Xs[64 * 64];
    __shared__ unsigned short Ws[3][64 * 64];

    f32x4 acc[3][4] = {};

    for (int k0 = 0; k0 < E_DIM; k0 += 64) {
        __syncthreads();
        #pragma unroll
        for (int j = 0; j < 4; ++j) {
            int p = j * 256 + tid;
            int row = p >> 4, c4 = (p & 15) * 4;
            float4 xv = *reinterpret_cast<const float4*>(
                &x[(size_t)(m0 + row) * E_DIM + k0 + c4]);
            uint2 wr;
            wr.x = pack2(f2bf(xv.x), f2bf(xv.y));
            wr.y = pack2(f2bf(xv.z), f2bf(xv.w));
            *reinterpret_cast<uint2*>(&Xs[swz(row, c4)]) = wr;
        }
        #pragma unroll
        for (int mat = 0; mat < 3; ++mat)
            #pragma unroll
            for (int j = 0; j < 2; ++j) {
                int p = j * 256 + tid;
                int n = p >> 3, c8 = (p & 7) * 8;
                uint4 w = *reinterpret_cast<const uint4*>(
                    &wt[((size_t)mat * H_DIM + n) * E_DIM + k0 + c8]);
                *reinterpret_cast<uint4*>(&Ws[mat][swz(n, c8)]) = w;
            }
        __syncthreads();
        #pragma unroll
        for (int hs = 0; hs < 2; ++hs) {
            short8_t a = *reinterpret_cast<const short8_t*>(
                &Xs[swz(wv * 16 + l15, hs * 32 + kof)]);
            #pragma unroll
            for (int mat = 0; mat < 3; ++mat)
                #pragma unroll
                for (int oc = 0; oc < 4; ++oc) {
                    short8_t b = *reinterpret_cast<const short8_t*>(
                        &Ws[mat][swz(oc * 16 + l15, hs * 32 + kof)]);
                    acc[mat][oc] = __builtin_amdgcn_mfma_f32_16x16x32_bf16(
                        a, b, acc[mat][oc], 0, 0, 0);
                }
        }
    }

    #pragma unroll
    for (int oc = 0; oc < 4; ++oc) {
        const int col = oc * 16 + l15;
        const float bqv = bq[col], bkv = bk[col], bvv = bv[col];
        #pragma unroll
        for (int r = 0; r < 4; ++r) {
            const int row = wv * 16 + lg * 4 + r;
            qb[(size_t)(m0 + row) * H_DIM + col] = f2bf((acc[0][oc][r] + bqv) * 0.125f);
            kb[(size_t)(m0 + row) * H_DIM + col] = f2bf(acc[1][oc][r] + bkv);
            vtb[((size_t)batch * H_DIM + col) * T_CTX + t0 + row] = f2bf(acc[2][oc][r] + bvv);
        }
    }
}

// ---------------------------------------------------------------------------
// Causal flash attention, bf16 MFMA, NO barriers, NO K/V LDS.
// One 16-row q strip per wave; K/V fragments loaded straight from global
// (L2/L3-resident, full 64B line utilization). K double-buffered in regs.
// 4 waves/block = same strip index, 4 batches -> perfectly balanced blocks;
// blocks dispatched in descending-work order.
// ---------------------------------------------------------------------------
#define ATTN_TILE(KC, KN, kt)                                                   \
  {                                                                             \
    const int k0_ = (kt) * 64;                                                  \
    if ((kt) + 1 < nkv) {                                                       \
      _Pragma("unroll")                                                         \
      for (int ct = 0; ct < 4; ++ct)                                            \
        _Pragma("unroll")                                                       \
        for (int hs = 0; hs < 2; ++hs)                                          \
          KN[ct * 2 + hs] = *reinterpret_cast<const short8_t*>(                 \
              &kg[(rbase + k0_ + 64 + ct * 16 + l15) * H_DIM + hs * 32 + kof]); \
    }                                                                           \
    short8_t vf[8];                                                             \
    _Pragma("unroll")                                                           \
    for (int oc = 0; oc < 4; ++oc)                                              \
      _Pragma("unroll")                                                         \
      for (int ks = 0; ks < 2; ++ks)                                            \
        vf[oc * 2 + ks] = *reinterpret_cast<const short8_t*>(                   \
            &vt[vbase + (size_t)(oc * 16 + l15) * T_CTX + k0_ + ks * 32 + kof]);\
    f32x4 s[4] = {};                                                            \
    _Pragma("unroll")                                                           \
    for (int hs = 0; hs < 2; ++hs)                                              \
      _Pragma("unroll")                                                         \
      for (int ct = 0; ct < 4; ++ct)                                            \
        s[ct] = __builtin_amdgcn_mfma_f32_16x16x32_bf16(qa[hs], KC[ct * 2 + hs],\
                                                        s[ct], 0, 0, 0);        \
    if ((kt) == nkv - 1) {                                                      \
      _Pragma("unroll")                                                         \
      for (int ct = 0; ct < 4; ++ct)                                            \
        _Pragma("unroll")                                                       \
        for (int r = 0; r < 4; ++r)                                             \
          if (k0_ + ct * 16 + l15 > q0 + lg * 4 + r) s[ct][r] = -1e30f;         \
    }                                                                           \
    _Pragma("unroll")                                                           \
    for (int r = 0; r < 4; ++r) {                                               \
      float mx = fmaxf(fmaxf(s[0][r], s[1][r]), fmaxf(s[2][r], s[3][r]));       \
      mx = fmaxf(mx, __shfl_xor(mx, 1));                                        \
      mx = fmaxf(mx, __shfl_xor(mx, 2));                                        \
      mx = fmaxf(mx, __shfl_xor(mx, 4));                                        \
      mx = fmaxf(mx, __shfl_xor(mx, 8));                                        \
      const float newm = fmaxf(mrow[r], mx);                                    \
      const float cf = __expf(mrow[r] - newm);                                  \
      float rl = 0.f;                                                           \
      _Pragma("unroll")                                                         \
      for (int ct = 0; ct < 4; ++ct) {                                          \
        float p = __expf(s[ct][r] - newm);                                      \
        rl += p;                                                                \
        Pt[pbase + swz(lg * 4 + r, ct * 16 + l15)] = f2bf(p);                   \
      }                                                                         \
      rl += __shfl_xor(rl, 1);                                                  \
      rl += __shfl_xor(rl, 2);                                                  \
      rl += __shfl_xor(rl, 4);                                                  \
      rl += __shfl_xor(rl, 8);                                                  \
      lrow[r] = lrow[r] * cf + rl;                                              \
      mrow[r] = newm;                                                           \
      _Pragma("unroll")                                                         \
      for (int oc = 0; oc < 4; ++oc) o[oc][r] *= cf;                            \
    }                                                                           \
    _Pragma("unroll")                                                           \
    for (int ks = 0; ks < 2; ++ks) {                                            \
      short8_t pa = *reinterpret_cast<const short8_t*>(                         \
          &Pt[pbase + swz(l15, ks * 32 + kof)]);                                \
      _Pragma("unroll")                                                         \
      for (int oc = 0; oc < 4; ++oc)                                            \
        o[oc] = __builtin_amdgcn_mfma_f32_16x16x32_bf16(pa, vf[oc * 2 + ks],    \
                                                        o[oc], 0, 0, 0);        \
    }                                                                           \
  }

__global__ __launch_bounds__(256, 1)
void attn_kernel(const unsigned short* __restrict__ qg,
                 const unsigned short* __restrict__ kg,
                 const unsigned short* __restrict__ vt,
                 float* __restrict__ outp)
{
    const int tid  = threadIdx.x;
    const int lane = tid & 63, wv = tid >> 6;
    const int l15 = lane & 15, lg = lane >> 4;
    const int kof = lg * 8;

    const int st    = 255 - blockIdx.x;     // strip index, heavy first
    const int batch = wv;                   // 4 waves = 4 batches, equal work
    const int q0    = st * 16;
    const int nkv   = st / 4 + 1;           // 64-wide kv tiles
    const size_t rbase = (size_t)batch * T_CTX;
    const size_t vbase = (size_t)batch * H_DIM * T_CTX;

    __shared__ unsigned short Pt[4 * 16 * 64];   // per-wave 2KB P buffer
    const int pbase = wv * 16 * 64;

    // Q fragments (q pre-scaled by 0.125 in proj)
    short8_t qa[2];
    #pragma unroll
    for (int hs = 0; hs < 2; ++hs)
        qa[hs] = *reinterpret_cast<const short8_t*>(
            &qg[(rbase + q0 + l15) * H_DIM + hs * 32 + kof]);

    f32x4 o[4] = {};
    float mrow[4] = {-1e30f, -1e30f, -1e30f, -1e30f};
    float lrow[4] = {};

    short8_t KA[8], KB[8];
    #pragma unroll
    for (int ct = 0; ct < 4; ++ct)
        #pragma unroll
        for (int hs = 0; hs < 2; ++hs)
            KA[ct * 2 + hs] = *reinterpret_cast<const short8_t*>(
                &kg[(rbase + ct * 16 + l15) * H_DIM + hs * 32 + kof]);

    int kt = 0;
    while (true) {
        ATTN_TILE(KA, KB, kt)
        ++kt;
        if (kt >= nkv) break;
        ATTN_TILE(KB, KA, kt)
        ++kt;
        if (kt >= nkv) break;
    }

    float inv[4];
    #pragma unroll
    for (int r = 0; r < 4; ++r) inv[r] = 1.0f / lrow[r];
    #pragma unroll
    for (int oc = 0; oc < 4; ++oc)
        #pragma unroll
        for (int r = 0; r < 4; ++r)
            outp[(rbase + q0 + lg * 4 + r) * H_DIM + oc * 16 + l15] = o[oc][r] * inv[r];
}

extern "C" void kernel_launch(void* const* d_in, const int* in_sizes, int n_in,
                              void* d_out, int out_size, void* d_ws, size_t ws_size,
                              hipStream_t stream) {
    const float* x  = (const float*)d_in[0];
    const float* Wq = (const float*)d_in[1];
    const float* bq = (const float*)d_in[2];
    const float* Wk = (const float*)d_in[3];
    const float* bk = (const float*)d_in[4];
    const float* Wv = (const float*)d_in[5];
    const float* bv = (const float*)d_in[6];
    float* out = (float*)d_out;

    // ws (ushort): Wt[3*64*1024] | q[16384*64] | k[16384*64] | vt[4*64*4096]
    unsigned short* wt  = (unsigned short*)d_ws;
    unsigned short* qb  = wt + 3 * H_DIM * E_DIM;
    unsigned short* kb  = qb + (size_t)M_ROWS * H_DIM;
    unsigned short* vtb = kb + (size_t)M_ROWS * H_DIM;

    prep_weights<<<dim3(E_DIM / 64, 3), 256, 0, stream>>>(Wq, Wk, Wv, wt);
    proj_kernel<<<dim3(M_ROWS / 64), 256, 0, stream>>>(x, wt, bq, bk, bv, qb, kb, vtb);
    attn_kernel<<<dim3(T_CTX / 16), 256, 0, stream>>>(qb, kb, vtb, out);
}

// Round 4
// 137.403 us; speedup vs baseline: 3.7035x; 1.3629x over previous
//
#include <hip/hip_runtime.h>

typedef __attribute__((ext_vector_type(8))) short short8_t;
typedef __attribute__((ext_vector_type(4))) float f32x4;

namespace {
constexpr int T_CTX  = 4096;
constexpr int E_DIM  = 1024;
constexpr int H_DIM  = 64;
constexpr int B_SZ   = 4;
constexpr int M_ROWS = B_SZ * T_CTX; // 16384
}

__device__ __forceinline__ unsigned short f2bf(float f) {
    unsigned u = __builtin_bit_cast(unsigned, f);
    u += 0x7fffu + ((u >> 16) & 1u);          // RNE
    return (unsigned short)(u >> 16);
}
__device__ __forceinline__ unsigned pack2(unsigned short lo, unsigned short hi) {
    return (unsigned)lo | ((unsigned)hi << 16);
}
// swizzled ushort index into a row-major [rows][64] bf16 LDS tile
__device__ __forceinline__ int swz(int row, int col) {
    return row * 64 + (col ^ ((row & 7) << 3));
}

// ---------------------------------------------------------------------------
// Weight prep: W[1024][64] fp32 -> Wt[64][1024] bf16 (per matrix), via LDS.
// ---------------------------------------------------------------------------
__global__ __launch_bounds__(256)
void prep_weights(const float* __restrict__ Wq, const float* __restrict__ Wk,
                  const float* __restrict__ Wv, unsigned short* __restrict__ wt)
{
    const int mat = blockIdx.y;
    const float* W = (mat == 0) ? Wq : (mat == 1) ? Wk : Wv;
    unsigned short* out = wt + (size_t)mat * H_DIM * E_DIM;
    __shared__ float Ls[64][65];
    const int tid = threadIdx.x;
    const int kb = blockIdx.x * 64;
    #pragma unroll
    for (int j = 0; j < 4; ++j) {
        int p = j * 256 + tid;
        int kr = p >> 4, c4 = (p & 15) * 4;
        float4 w4 = *reinterpret_cast<const float4*>(&W[(size_t)(kb + kr) * H_DIM + c4]);
        Ls[c4 + 0][kr] = w4.x; Ls[c4 + 1][kr] = w4.y;
        Ls[c4 + 2][kr] = w4.z; Ls[c4 + 3][kr] = w4.w;
    }
    __syncthreads();
    #pragma unroll
    for (int j = 0; j < 2; ++j) {
        int p = j * 256 + tid;
        int n = p >> 3, c8 = (p & 7) * 8;
        uint4 w;
        w.x = pack2(f2bf(Ls[n][c8 + 0]), f2bf(Ls[n][c8 + 1]));
        w.y = pack2(f2bf(Ls[n][c8 + 2]), f2bf(Ls[n][c8 + 3]));
        w.z = pack2(f2bf(Ls[n][c8 + 4]), f2bf(Ls[n][c8 + 5]));
        w.w = pack2(f2bf(Ls[n][c8 + 6]), f2bf(Ls[n][c8 + 7]));
        *reinterpret_cast<uint4*>(&out[(size_t)n * E_DIM + kb + c8]) = w;
    }
}

// ---------------------------------------------------------------------------
// Fused QKV projection, barrier-free streaming. One wave = 16 rows, all 3
// mats, K=1024 in 32-chunks. A: fp32 x loads -> in-reg bf16. B: direct
// short8 loads from pre-transposed Wt (L1/L2-resident). No LDS, no barriers.
// q pre-scaled by 0.125; v written transposed vt[b][h][t].
// ---------------------------------------------------------------------------
__global__ __launch_bounds__(256)
void proj_kernel(const float* __restrict__ x, const unsigned short* __restrict__ wt,
                 const float* __restrict__ bq, const float* __restrict__ bk,
                 const float* __restrict__ bv,
                 unsigned short* __restrict__ qb, unsigned short* __restrict__ kb,
                 unsigned short* __restrict__ vtb)
{
    const int tid = threadIdx.x;
    const int lane = tid & 63, wv = tid >> 6;
    const int l15 = lane & 15, lg = lane >> 4;
    const int kof = lg * 8;

    const int task = blockIdx.x * 4 + wv;     // 0..1023
    const int m0   = task * 16;
    const int batch = m0 >> 12;
    const int t0    = m0 & (T_CTX - 1);

    f32x4 acc[3][4] = {};

    const float* xrow = &x[(size_t)(m0 + l15) * E_DIM + kof];

    for (int k0 = 0; k0 < E_DIM; k0 += 32) {
        const float4 xa = *reinterpret_cast<const float4*>(xrow + k0);
        const float4 xb = *reinterpret_cast<const float4*>(xrow + k0 + 4);
        short8_t a;
        a[0] = (short)f2bf(xa.x); a[1] = (short)f2bf(xa.y);
        a[2] = (short)f2bf(xa.z); a[3] = (short)f2bf(xa.w);
        a[4] = (short)f2bf(xb.x); a[5] = (short)f2bf(xb.y);
        a[6] = (short)f2bf(xb.z); a[7] = (short)f2bf(xb.w);
        #pragma unroll
        for (int mat = 0; mat < 3; ++mat)
            #pragma unroll
            for (int oc = 0; oc < 4; ++oc) {
                short8_t b = *reinterpret_cast<const short8_t*>(
                    &wt[((size_t)mat * H_DIM + oc * 16 + l15) * E_DIM + k0 + kof]);
                acc[mat][oc] = __builtin_amdgcn_mfma_f32_16x16x32_bf16(
                    a, b, acc[mat][oc], 0, 0, 0);
            }
    }

    #pragma unroll
    for (int oc = 0; oc < 4; ++oc) {
        const int col = oc * 16 + l15;
        const float bqv = bq[col], bkv = bk[col], bvv = bv[col];
        #pragma unroll
        for (int r = 0; r < 4; ++r) {
            const int row = lg * 4 + r;
            qb[(size_t)(m0 + row) * H_DIM + col] = f2bf((acc[0][oc][r] + bqv) * 0.125f);
            kb[(size_t)(m0 + row) * H_DIM + col] = f2bf(acc[1][oc][r] + bkv);
            vtb[((size_t)batch * H_DIM + col) * T_CTX + t0 + row] = f2bf(acc[2][oc][r] + bvv);
        }
    }
}

// ---------------------------------------------------------------------------
// Causal flash attention, split-KV within block. Block = (strip, batch);
// 4 waves take kv tiles round-robin (kt = wv, wv+4, ...), private (m,l,o);
// single barrier + LDS log-sum-exp merge at the end. No barriers in loop.
// ---------------------------------------------------------------------------
__global__ __launch_bounds__(256, 4)
void attn_kernel(const unsigned short* __restrict__ qg,
                 const unsigned short* __restrict__ kg,
                 const unsigned short* __restrict__ vt,
                 float* __restrict__ outp)
{
    const int tid  = threadIdx.x;
    const int lane = tid & 63, wv = tid >> 6;
    const int l15 = lane & 15, lg = lane >> 4;
    const int kof = lg * 8;

    const int idx   = 1023 - blockIdx.x;     // heavy strips first
    const int st    = idx >> 2;              // 0..255
    const int batch = idx & 3;
    const int q0    = st * 16;
    const int nkv   = st / 4 + 1;            // 64-wide kv tiles
    const size_t rbase = (size_t)batch * T_CTX;
    const size_t vbase = (size_t)batch * H_DIM * T_CTX;

    __shared__ unsigned short Pt[4 * 16 * 64];   // per-wave 2KB P buffer
    __shared__ float Lo[4][16][64];              // merge buffers
    __shared__ float Lm[4][16];
    __shared__ float Ll[4][16];
    const int pbase = wv * 16 * 64;

    // Q fragments (q pre-scaled by 0.125 in proj)
    short8_t qa[2];
    #pragma unroll
    for (int hs = 0; hs < 2; ++hs)
        qa[hs] = *reinterpret_cast<const short8_t*>(
            &qg[(rbase + q0 + l15) * H_DIM + hs * 32 + kof]);

    f32x4 o[4] = {};
    float mrow[4] = {-1e30f, -1e30f, -1e30f, -1e30f};
    float lrow[4] = {};

    for (int kt = wv; kt < nkv; kt += 4) {
        const int k0 = kt * 64;

        // V fragments first (consumed last -> longest latency tolerance)
        short8_t vf[8];
        #pragma unroll
        for (int oc = 0; oc < 4; ++oc)
            #pragma unroll
            for (int ks = 0; ks < 2; ++ks)
                vf[oc * 2 + ks] = *reinterpret_cast<const short8_t*>(
                    &vt[vbase + (size_t)(oc * 16 + l15) * T_CTX + k0 + ks * 32 + kof]);

        // S = Q K^T  (K fragments short-lived, per-hs)
        f32x4 s[4] = {};
        #pragma unroll
        for (int hs = 0; hs < 2; ++hs) {
            short8_t kf[4];
            #pragma unroll
            for (int ct = 0; ct < 4; ++ct)
                kf[ct] = *reinterpret_cast<const short8_t*>(
                    &kg[(rbase + k0 + ct * 16 + l15) * H_DIM + hs * 32 + kof]);
            #pragma unroll
            for (int ct = 0; ct < 4; ++ct)
                s[ct] = __builtin_amdgcn_mfma_f32_16x16x32_bf16(
                    qa[hs], kf[ct], s[ct], 0, 0, 0);
        }

        if (kt == nkv - 1) {    // only the last strip tile crosses the diagonal
            #pragma unroll
            for (int ct = 0; ct < 4; ++ct)
                #pragma unroll
                for (int r = 0; r < 4; ++r)
                    if (k0 + ct * 16 + l15 > q0 + lg * 4 + r) s[ct][r] = -1e30f;
        }

        // online softmax (wave-local)
        #pragma unroll
        for (int r = 0; r < 4; ++r) {
            float mx = fmaxf(fmaxf(s[0][r], s[1][r]), fmaxf(s[2][r], s[3][r]));
            mx = fmaxf(mx, __shfl_xor(mx, 1));
            mx = fmaxf(mx, __shfl_xor(mx, 2));
            mx = fmaxf(mx, __shfl_xor(mx, 4));
            mx = fmaxf(mx, __shfl_xor(mx, 8));
            const float newm = fmaxf(mrow[r], mx);
            const float cf = __expf(mrow[r] - newm);
            float rl = 0.f;
            #pragma unroll
            for (int ct = 0; ct < 4; ++ct) {
                float p = __expf(s[ct][r] - newm);
                rl += p;
                Pt[pbase + swz(lg * 4 + r, ct * 16 + l15)] = f2bf(p);
            }
            rl += __shfl_xor(rl, 1);
            rl += __shfl_xor(rl, 2);
            rl += __shfl_xor(rl, 4);
            rl += __shfl_xor(rl, 8);
            lrow[r] = lrow[r] * cf + rl;
            mrow[r] = newm;
            #pragma unroll
            for (int oc = 0; oc < 4; ++oc) o[oc][r] *= cf;
        }

        // O += P V
        #pragma unroll
        for (int ks = 0; ks < 2; ++ks) {
            short8_t pa = *reinterpret_cast<const short8_t*>(
                &Pt[pbase + swz(l15, ks * 32 + kof)]);
            #pragma unroll
            for (int oc = 0; oc < 4; ++oc)
                o[oc] = __builtin_amdgcn_mfma_f32_16x16x32_bf16(
                    pa, vf[oc * 2 + ks], o[oc], 0, 0, 0);
        }
    }

    // publish partials
    #pragma unroll
    for (int oc = 0; oc < 4; ++oc)
        #pragma unroll
        for (int r = 0; r < 4; ++r)
            Lo[wv][lg * 4 + r][oc * 16 + l15] = o[oc][r];
    if (l15 == 0) {
        #pragma unroll
        for (int r = 0; r < 4; ++r) {
            Lm[wv][lg * 4 + r] = mrow[r];
            Ll[wv][lg * 4 + r] = lrow[r];
        }
    }
    __syncthreads();

    // merge: thread -> (row, 4 cols). Coalesced float4 output store.
    {
        const int row = tid >> 4;
        const int c4  = (tid & 15) * 4;
        float M = -1e30f;
        #pragma unroll
        for (int w = 0; w < 4; ++w) M = fmaxf(M, Lm[w][row]);
        float L = 0.f;
        float a0 = 0.f, a1 = 0.f, a2 = 0.f, a3 = 0.f;
        #pragma unroll
        for (int w = 0; w < 4; ++w) {
            const float e = __expf(Lm[w][row] - M);
            L += e * Ll[w][row];
            const float4 ov = *reinterpret_cast<const float4*>(&Lo[w][row][c4]);
            a0 += e * ov.x; a1 += e * ov.y; a2 += e * ov.z; a3 += e * ov.w;
        }
        const float inv = 1.0f / L;
        float4 rr;
        rr.x = a0 * inv; rr.y = a1 * inv; rr.z = a2 * inv; rr.w = a3 * inv;
        *reinterpret_cast<float4*>(&outp[(rbase + q0 + row) * H_DIM + c4]) = rr;
    }
}

extern "C" void kernel_launch(void* const* d_in, const int* in_sizes, int n_in,
                              void* d_out, int out_size, void* d_ws, size_t ws_size,
                              hipStream_t stream) {
    const float* x  = (const float*)d_in[0];
    const float* Wq = (const float*)d_in[1];
    const float* bq = (const float*)d_in[2];
    const float* Wk = (const float*)d_in[3];
    const float* bk = (const float*)d_in[4];
    const float* Wv = (const float*)d_in[5];
    const float* bv = (const float*)d_in[6];
    float* out = (float*)d_out;

    // ws (ushort): Wt[3*64*1024] | q[16384*64] | k[16384*64] | vt[4*64*4096]
    unsigned short* wt  = (unsigned short*)d_ws;
    unsigned short* qb  = wt + 3 * H_DIM * E_DIM;
    unsigned short* kb  = qb + (size_t)M_ROWS * H_DIM;
    unsigned short* vtb = kb + (size_t)M_ROWS * H_DIM;

    prep_weights<<<dim3(E_DIM / 64, 3), 256, 0, stream>>>(Wq, Wk, Wv, wt);
    proj_kernel<<<dim3(M_ROWS / 64), 256, 0, stream>>>(x, wt, bq, bk, bv, qb, kb, vtb);
    attn_kernel<<<dim3((T_CTX / 16) * B_SZ), 256, 0, stream>>>(qb, kb, vtb, out);
}